// Round 1
// baseline (17.995 us; speedup 1.0000x reference)
//
#include <hip/hip_runtime.h>
#include <math.h>

// Sliding-window (n=64) temperature-softmax attention over 1D fp32 sequence.
// Segmented online-softmax scan: segment L=32, one thread per segment.
// Window [i-63, i] with i = 32*s + p decomposes as
//   suffix(seg s-2, elems p+1..31)  ⊕  prefix(seg s-1 full ∥ seg s elems 0..p)
// Triple (m, s0=Σe^{(v-m)/τ}, s1=Σ v e^{(v-m)/τ}) is an associative monoid.
// Suffix triples (31 of them) live in registers via full unroll (static idx).

#define SEG 32

__device__ __forceinline__ float fexp2(float x) { return __builtin_amdgcn_exp2f(x); }

__global__ __launch_bounds__(256, 2) void soft_attn_kernel(
    const float* __restrict__ x, const float* __restrict__ w_tau,
    float* __restrict__ out, int nseg)
{
    const int s = blockIdx.x * blockDim.x + threadIdx.x;
    if (s >= nseg) return;

    const float tau = log1pf(expf(w_tau[0])) + 1e-5f;
    const float C = 1.4426950408889634f / tau;   // log2(e)/tau

    // Suffix triples of segment s-2: idx q holds scan of elems [q+1 .. 31].
    // q = 31 stays empty (window at p=31 has no suffix part).
    float Sm[SEG], Sa[SEG], Sb[SEG];
#pragma unroll
    for (int q = 0; q < SEG; ++q) { Sm[q] = -INFINITY; Sa[q] = 0.f; Sb[q] = 0.f; }

    float v[SEG];

    if (s >= 2) {
        const float4* p4 = reinterpret_cast<const float4*>(x + (size_t)(s - 2) * SEG);
#pragma unroll
        for (int k = 0; k < SEG / 4; ++k) {
            float4 t = p4[k];
            v[4*k+0] = t.x; v[4*k+1] = t.y; v[4*k+2] = t.z; v[4*k+3] = t.w;
        }
        float m = -INFINITY, a0 = 0.f, a1 = 0.f;
#pragma unroll
        for (int q = SEG - 1; q >= 1; --q) {
            const float val = v[q];
            const float nm = fmaxf(m, val);
            const float ea = fexp2((val - nm) * C);   // =1 if val is new max
            const float eb = fexp2((m   - nm) * C);   // =1 if max unchanged; exp2(-inf)=0 seeds
            a0 = a0 * eb + ea;
            a1 = a1 * eb + val * ea;
            m = nm;
            Sm[q-1] = m; Sa[q-1] = a0; Sb[q-1] = a1;
        }
    }

    // Running prefix over segment s-1 (full) then segment s (emitting outputs).
    float m = -INFINITY, r0 = 0.f, r1 = 0.f;
    if (s >= 1) {
        const float4* p4 = reinterpret_cast<const float4*>(x + (size_t)(s - 1) * SEG);
#pragma unroll
        for (int k = 0; k < SEG / 4; ++k) {
            float4 t = p4[k];
            v[4*k+0] = t.x; v[4*k+1] = t.y; v[4*k+2] = t.z; v[4*k+3] = t.w;
        }
#pragma unroll
        for (int q = 0; q < SEG; ++q) {
            const float val = v[q];
            const float nm = fmaxf(m, val);
            const float ea = fexp2((val - nm) * C);
            const float eb = fexp2((m   - nm) * C);
            r0 = r0 * eb + ea;
            r1 = r1 * eb + val * ea;
            m = nm;
        }
    }
    {
        const float4* p4 = reinterpret_cast<const float4*>(x + (size_t)s * SEG);
#pragma unroll
        for (int k = 0; k < SEG / 4; ++k) {
            float4 t = p4[k];
            v[4*k+0] = t.x; v[4*k+1] = t.y; v[4*k+2] = t.z; v[4*k+3] = t.w;
        }
    }

    float4* o4 = reinterpret_cast<float4*>(out + (size_t)s * SEG);
    float4 ob;
#pragma unroll
    for (int p = 0; p < SEG; ++p) {
        const float val = v[p];
        const float nm = fmaxf(m, val);
        const float ea = fexp2((val - nm) * C);
        const float eb = fexp2((m   - nm) * C);
        r0 = r0 * eb + ea;
        r1 = r1 * eb + val * ea;
        m = nm;
        // combine prefix (m,r0,r1) with suffix triple at p
        const float sm = Sm[p];
        const float mm = fmaxf(m, sm);
        const float e1 = fexp2((m  - mm) * C);
        const float e2 = fexp2((sm - mm) * C);   // 0 when suffix empty (sm=-inf)
        const float t0 = r0 * e1 + Sa[p] * e2;
        const float t1 = r1 * e1 + Sb[p] * e2;
        const float res = t1 * __builtin_amdgcn_rcpf(t0);  // t0 in [1,64]: well-conditioned
        if      ((p & 3) == 0) ob.x = res;
        else if ((p & 3) == 1) ob.y = res;
        else if ((p & 3) == 2) ob.z = res;
        else { ob.w = res; o4[p >> 2] = ob; }
    }
}

extern "C" void kernel_launch(void* const* d_in, const int* in_sizes, int n_in,
                              void* d_out, int out_size, void* d_ws, size_t ws_size,
                              hipStream_t stream) {
    const float* x = (const float*)d_in[0];
    const float* w = (const float*)d_in[1];
    float* out = (float*)d_out;
    const int N = in_sizes[0];            // 4194304, divisible by SEG=32
    const int nseg = N / SEG;
    const int threads = 256;
    const int blocks = (nseg + threads - 1) / threads;
    soft_attn_kernel<<<blocks, threads, 0, stream>>>(x, w, out, nseg);
}

// Round 2
// 17.753 us; speedup vs baseline: 1.0136x; 1.0136x over previous
//
#include <hip/hip_runtime.h>
#include <math.h>

// Sliding-window (n=64) temperature-softmax attention, fp32, N=4194304.
// Segmented two-sided online-softmax scan, SEG=16, one thread per segment.
// Window for output i = 16*s + p:
//   suffix(seg s-4, elems p+1..15)  ⊕  prefix(segs s-3,s-2,s-1 full ∥ seg s elems 0..p)
// Monoid triple: (m, Σ e^{(v-m)/τ}, Σ v e^{(v-m)/τ}).
// One exp2 per element: of (ea, eb) one is always exactly 1.0.

#define SEG 16

__device__ __forceinline__ float fexp2(float x) { return __builtin_amdgcn_exp2f(x); }

__global__ __launch_bounds__(256, 3) void soft_attn_kernel(
    const float* __restrict__ x, const float* __restrict__ w_tau,
    float* __restrict__ out)
{
    const int s = blockIdx.x * blockDim.x + threadIdx.x;
    const float tau = log1pf(expf(w_tau[0])) + 1e-5f;
    const float C = 1.4426950408889634f / tau;   // log2(e)/tau

    // Emission segment values (segment s always exists).
    float ve[SEG];
    {
        const float4* p4 = reinterpret_cast<const float4*>(x + (size_t)s * SEG);
#pragma unroll
        for (int k = 0; k < SEG / 4; ++k) {
            float4 t = p4[k];
            ve[4*k] = t.x; ve[4*k+1] = t.y; ve[4*k+2] = t.z; ve[4*k+3] = t.w;
        }
    }

    float Sm[SEG], Sa[SEG], Sb[SEG];          // suffix triples of seg s-4, idx p = start p+1
    float m = -INFINITY, r0 = 0.f, r1 = 0.f;  // running prefix triple

    if (s >= 4) {
        // Fast straight-line path: all 4 preceding segments exist.
        float v0[SEG], v1[3 * SEG];
        {
            const float4* p4 = reinterpret_cast<const float4*>(x + (size_t)(s - 4) * SEG);
#pragma unroll
            for (int k = 0; k < SEG / 4; ++k) {
                float4 t = p4[k];
                v0[4*k] = t.x; v0[4*k+1] = t.y; v0[4*k+2] = t.z; v0[4*k+3] = t.w;
            }
        }
        {
            const float4* p4 = reinterpret_cast<const float4*>(x + (size_t)(s - 3) * SEG);
#pragma unroll
            for (int k = 0; k < 3 * SEG / 4; ++k) {
                float4 t = p4[k];
                v1[4*k] = t.x; v1[4*k+1] = t.y; v1[4*k+2] = t.z; v1[4*k+3] = t.w;
            }
        }
        // Suffix scan over v0 (seg s-4), storing triples for starts 1..15.
        float sm = -INFINITY, sa = 0.f, sb = 0.f;
#pragma unroll
        for (int q = SEG - 1; q >= 1; --q) {
            const float val = v0[q];
            const float nm = fmaxf(sm, val);
            const float e  = fexp2(-fabsf(sm - val) * C);  // exp2(-inf)=0 seeds correctly
            const float ea = (val >= sm) ? 1.f : e;
            const float eb = (val >= sm) ? e : 1.f;
            sa = sa * eb + ea;
            sb = sb * eb + val * ea;
            sm = nm;
            Sm[q-1] = sm; Sa[q-1] = sa; Sb[q-1] = sb;
        }
        Sm[SEG-1] = -INFINITY; Sa[SEG-1] = 0.f; Sb[SEG-1] = 0.f;  // empty suffix (p=15)
        // Prefix scan over segs s-3, s-2, s-1 (48 elements).
#pragma unroll
        for (int q = 0; q < 3 * SEG; ++q) {
            const float val = v1[q];
            const float nm = fmaxf(m, val);
            const float e  = fexp2(-fabsf(m - val) * C);
            const float ea = (val >= m) ? 1.f : e;
            const float eb = (val >= m) ? e : 1.f;
            r0 = r0 * eb + ea;
            r1 = r1 * eb + val * ea;
            m = nm;
        }
    } else {
        // Slow guarded path: only threads s = 0..3 (first wave of block 0).
#pragma unroll
        for (int q = 0; q < SEG; ++q) { Sm[q] = -INFINITY; Sa[q] = 0.f; Sb[q] = 0.f; }
        for (int j = 0; j < 3; ++j) {
            const int t = s - 3 + j;
            if (t >= 0) {
                const float* p = x + (size_t)t * SEG;
                for (int q = 0; q < SEG; ++q) {
                    const float val = p[q];
                    const float nm = fmaxf(m, val);
                    const float e  = fexp2(-fabsf(m - val) * C);
                    const float ea = (val >= m) ? 1.f : e;
                    const float eb = (val >= m) ? e : 1.f;
                    r0 = r0 * eb + ea;
                    r1 = r1 * eb + val * ea;
                    m = nm;
                }
            }
        }
    }

    // Emission: continue prefix over seg s, combining with stored suffix triples.
    float4* o4 = reinterpret_cast<float4*>(out + (size_t)s * SEG);
    float4 ob;
#pragma unroll
    for (int p = 0; p < SEG; ++p) {
        const float val = ve[p];
        const float nm = fmaxf(m, val);
        const float e  = fexp2(-fabsf(m - val) * C);
        const float ea = (val >= m) ? 1.f : e;
        const float eb = (val >= m) ? e : 1.f;
        r0 = r0 * eb + ea;
        r1 = r1 * eb + val * ea;
        m = nm;
        // Combine running prefix (m,r0,r1) with suffix triple at p.
        const float smv = Sm[p];
        const float mm  = fmaxf(m, smv);       (void)mm;
        const float ec  = fexp2(-fabsf(m - smv) * C);
        const float e1  = (m >= smv) ? 1.f : ec;
        const float e2  = (m >= smv) ? ec : 1.f;
        const float t0  = r0 * e1 + Sa[p] * e2;
        const float t1  = r1 * e1 + Sb[p] * e2;
        const float res = t1 * __builtin_amdgcn_rcpf(t0);  // t0 in [1,64]: well-conditioned
        if      ((p & 3) == 0) ob.x = res;
        else if ((p & 3) == 1) ob.y = res;
        else if ((p & 3) == 2) ob.z = res;
        else { ob.w = res; o4[p >> 2] = ob; }
    }
}

extern "C" void kernel_launch(void* const* d_in, const int* in_sizes, int n_in,
                              void* d_out, int out_size, void* d_ws, size_t ws_size,
                              hipStream_t stream) {
    const float* x = (const float*)d_in[0];
    const float* w = (const float*)d_in[1];
    float* outp = (float*)d_out;
    const int N = in_sizes[0];                 // 4194304, divisible by SEG
    const int nseg = N / SEG;                  // 262144
    const int threads = 256;
    const int blocks = (nseg + threads - 1) / threads;   // 1024
    soft_attn_kernel<<<blocks, threads, 0, stream>>>(x, w, outp);
}